// Round 4
// baseline (98.847 us; speedup 1.0000x reference)
//
#include <hip/hip_runtime.h>
#include <hip/hip_bf16.h>
#include <cstdint>

#define N1 4096
#define N2 4096
#define DD 256
#define DELTA 1.0f
#define EPSN 1e-8f

#define BM 128
#define BN 128
#define BK 64

#define NBLK ((N1 / BM) * (N2 / BN))   // 1024 GEMM blocks

typedef __attribute__((ext_vector_type(8))) __bf16 bf16x8;
typedef __attribute__((ext_vector_type(4))) float f32x4;

typedef const __attribute__((address_space(1))) void* gptr_t;
typedef __attribute__((address_space(3))) void* lptr_t;

// Kernel 1: row-normalize fp32 -> bf16 (torch-style eps clamp), float4-vectorized.
// One wave per row, 4 rows per block. Also zeroes ws accumulator + completion counter.
__global__ __launch_bounds__(256) void normalize_kernel(
    const float* __restrict__ mmd1, const float* __restrict__ mmd2,
    ushort* __restrict__ out1, ushort* __restrict__ out2,
    float* __restrict__ ws_sum, unsigned int* __restrict__ ws_count)
{
    const int wid = threadIdx.x >> 6, lane = threadIdx.x & 63;
    const int row = blockIdx.x * 4 + wid;

    const float* srcp;
    ushort* dstp;
    if (row < N1) { srcp = mmd1 + (size_t)row * DD;        dstp = out1 + (size_t)row * DD; }
    else          { srcp = mmd2 + (size_t)(row - N1) * DD; dstp = out2 + (size_t)(row - N1) * DD; }

    float4 v = reinterpret_cast<const float4*>(srcp)[lane];
    float ss = v.x * v.x + v.y * v.y + v.z * v.z + v.w * v.w;
    #pragma unroll
    for (int off = 32; off; off >>= 1) ss += __shfl_xor(ss, off, 64);  // butterfly
    float scale = 1.0f / fmaxf(sqrtf(ss), EPSN);

    __hip_bfloat16 b0 = __float2bfloat16(v.x * scale);
    __hip_bfloat16 b1 = __float2bfloat16(v.y * scale);
    __hip_bfloat16 b2 = __float2bfloat16(v.z * scale);
    __hip_bfloat16 b3 = __float2bfloat16(v.w * scale);
    ushort4 o;
    o.x = *reinterpret_cast<const ushort*>(&b0);
    o.y = *reinterpret_cast<const ushort*>(&b1);
    o.z = *reinterpret_cast<const ushort*>(&b2);
    o.w = *reinterpret_cast<const ushort*>(&b3);
    reinterpret_cast<ushort4*>(dstp)[lane] = o;

    if (blockIdx.x == 0 && threadIdx.x == 0) { ws_sum[0] = 0.0f; ws_count[0] = 0u; }
}

// Kernel 2: C = A * B^T on bf16 via MFMA (XOR-chunk-swizzled LDS), fused
// label-hinge + mean-sum epilogue, last-block writes the final mean.
__global__ __launch_bounds__(256) void cos_gemm_kernel(
    const ushort* __restrict__ A, const ushort* __restrict__ B,
    const int* __restrict__ lab1, const int* __restrict__ lab2,
    float* __restrict__ ws_sum, unsigned int* __restrict__ ws_count,
    float* __restrict__ out)
{
    __shared__ __align__(16) ushort As[BM * BK];  // 16 KB
    __shared__ __align__(16) ushort Bs[BN * BK];  // 16 KB
    __shared__ int l1s[BM];
    __shared__ int l2s[BN];
    __shared__ float wredsum[4];

    const int row0 = blockIdx.y * BM;
    const int col0 = blockIdx.x * BN;
    const int t = threadIdx.x;
    const int lane = t & 63, wid = t >> 6;
    const int wr = wid >> 1, wc = wid & 1;   // wave -> 64x64 quadrant

    if (t < BM) l1s[t] = lab1[row0 + t];
    else        l2s[t - BM] = lab2[col0 + (t - BM)];

    f32x4 acc[4][4] = {};

    for (int k0 = 0; k0 < DD; k0 += BK) {
        __syncthreads();  // previous compute done before overwriting LDS
        // 1024 16B-chunks per matrix; LDS dest linear, global source XOR-swizzled:
        // LDS chunk c of row r holds global chunk c^(r&7)  (both-sides involution).
        #pragma unroll
        for (int it = 0; it < 4; ++it) {
            int idx = t + it * 256;
            int r = idx >> 3;
            int c = idx & 7;
            int gc = c ^ (r & 7);
            __builtin_amdgcn_global_load_lds(
                (gptr_t)(A + (size_t)(row0 + r) * DD + k0 + gc * 8),
                (lptr_t)(&As[r * BK + c * 8]), 16, 0, 0);
            __builtin_amdgcn_global_load_lds(
                (gptr_t)(B + (size_t)(col0 + r) * DD + k0 + gc * 8),
                (lptr_t)(&Bs[r * BK + c * 8]), 16, 0, 0);
        }
        __syncthreads();  // staging complete

        #pragma unroll
        for (int kk = 0; kk < 2; ++kk) {     // two 32-wide K substeps
            const int ck = kk * 4 + (lane >> 4);
            const int rsel = lane & 15;
            bf16x8 af[4], bfr[4];
            #pragma unroll
            for (int m = 0; m < 4; ++m) {
                int R = wr * 64 + m * 16 + rsel;
                af[m] = *reinterpret_cast<const bf16x8*>(&As[R * BK + (ck ^ (R & 7)) * 8]);
            }
            #pragma unroll
            for (int n = 0; n < 4; ++n) {
                int R = wc * 64 + n * 16 + rsel;
                bfr[n] = *reinterpret_cast<const bf16x8*>(&Bs[R * BK + (ck ^ (R & 7)) * 8]);
            }
            #pragma unroll
            for (int m = 0; m < 4; ++m)
                #pragma unroll
                for (int n = 0; n < 4; ++n)
                    acc[m][n] = __builtin_amdgcn_mfma_f32_16x16x32_bf16(af[m], bfr[n], acc[m][n], 0, 0, 0);
        }
    }

    // Epilogue: C/D mapping col = lane&15, row = (lane>>4)*4 + reg  (m89)
    float lsum = 0.0f;
    const int csel = lane & 15;
    #pragma unroll
    for (int n = 0; n < 4; ++n) {
        int j = wc * 64 + n * 16 + csel;
        int l2 = l2s[j];
        #pragma unroll
        for (int m = 0; m < 4; ++m) {
            int ibase = wr * 64 + m * 16 + (lane >> 4) * 4;
            #pragma unroll
            for (int e = 0; e < 4; ++e) {
                float cosv = acc[m][n][e];
                float v = (l1s[ibase + e] == l2) ? fmaxf(DELTA - cosv, 0.0f) : cosv;
                lsum += v;
            }
        }
    }
    #pragma unroll
    for (int off = 32; off; off >>= 1) lsum += __shfl_down(lsum, off, 64);
    if (lane == 0) wredsum[wid] = lsum;
    __syncthreads();

    // Last-block finalize: dispatch-order-free, no co-residency requirement.
    if (t == 0) {
        atomicAdd(ws_sum, wredsum[0] + wredsum[1] + wredsum[2] + wredsum[3]);
        __threadfence();                                   // release partial sum
        unsigned int old = atomicAdd(ws_count, 1u);
        if (old == NBLK - 1) {                             // I'm the last block
            float total = atomicAdd(ws_sum, 0.0f);         // atomic read of final sum
            out[0] = total * (1.0f / ((float)N1 * (float)N2));
        }
    }
}

extern "C" void kernel_launch(void* const* d_in, const int* in_sizes, int n_in,
                              void* d_out, int out_size, void* d_ws, size_t ws_size,
                              hipStream_t stream) {
    const float* mmd1 = (const float*)d_in[0];
    const float* mmd2 = (const float*)d_in[1];
    const int* lab1 = (const int*)d_in[2];
    const int* lab2 = (const int*)d_in[3];

    ushort* n1b = (ushort*)d_ws;                       // 2 MB
    ushort* n2b = n1b + (size_t)N1 * DD;               // 2 MB
    float* ws_sum = (float*)((char*)d_ws + (size_t)(N1 + N2) * DD * 2);
    unsigned int* ws_count = (unsigned int*)(ws_sum + 1);
    float* out = (float*)d_out;

    normalize_kernel<<<(N1 + N2) / 4, 256, 0, stream>>>(mmd1, mmd2, n1b, n2b, ws_sum, ws_count);
    cos_gemm_kernel<<<dim3(N2 / BN, N1 / BM), 256, 0, stream>>>(n1b, n2b, lab1, lab2, ws_sum, ws_count, out);
}